// Round 6
// baseline (107.389 us; speedup 1.0000x reference)
//
#include <hip/hip_runtime.h>

#define UNITS 14336
#define IN_F 4096
#define PACKED 1024
#define CLIP_VAL 100.0f

typedef unsigned int uint32;

using bf16x8 = __attribute__((ext_vector_type(8))) short;   // 8 bf16 = 4 VGPRs
using f32x4  = __attribute__((ext_vector_type(4))) float;   // 4 fp32 acc

// fp32 -> bf16 round-to-nearest-even
__device__ inline unsigned short f2bf(float f) {
    uint32 u = __float_as_uint(f);
    u += 0x7FFFu + ((u >> 16) & 1u);
    return (unsigned short)(u >> 16);
}

__device__ inline uint32 pack2bf(float a, float b) {
    return (uint32)f2bf(a) | ((uint32)f2bf(b) << 16);
}

// SWAR unpack: one packed byte (int32 value 0..255, 4 crumbs little-endian)
// -> two uint32, each holding 2 bf16: r0 = {bf(c0), bf(c1)}, r1 = {bf(c2), bf(c3)}.
// crumb->bf16: 0->0x0000, 1->0x3F80 (+1), 2->0xBF80 (-1), 3->0x8000 (-0.0, harmless in MAC)
__device__ inline void unpack_byte(int v, uint32& r0, uint32& r1) {
    uint32 t0 = ((uint32)v & 3u) | (((uint32)v & 0xCu) << 14);         // c0 @ [1:0], c1 @ [17:16]
    uint32 t1 = (((uint32)v >> 4) & 3u) | (((uint32)v & 0xC0u) << 10); // c2, c3
    uint32 s0 = t0 >> 1;
    uint32 s1 = t1 >> 1;
    uint32 nz0 = (t0 ^ s0) & 0x00010001u;
    uint32 nz1 = (t1 ^ s1) & 0x00010001u;
    r0 = nz0 * 0x3F80u + ((s0 & 0x00010001u) << 15);
    r1 = nz1 * 0x3F80u + ((s1 & 0x00010001u) << 15);
}

__device__ inline float clipf(float y) {
    return fminf(fmaxf(y, -CLIP_VAL), CLIP_VAL);
}

// k-permuted fragment layout (unchanged from R4/R5):
// "group" g in [0,64) covers original k in [g*64, g*64+64).
// Within a group, lane quad q and k-step s in {0,1}:
//   MFMA k-slot q*8+j  <->  original k = g*64 + q*16 + s*8 + j
// pw side: lane(q,n) reads one dwordx4 = int32 elements {P..P+3}, P = g*16 + q*4;
//   elements P,P+1 -> step s=0 fragment, elements P+2,P+3 -> step s=1 fragment.
// x side: granule idx = g*256 + s*128 + h*64 + lane holds 8 bf16:
//   j -> x[h*16 + (lane&15)][g*64 + (lane>>4)*16 + s*8 + j]

// Kernel 1: convert x fp32 -> bf16 permuted fragments, replicated 8x
// (one copy per XCD; MM block c=blockIdx&7 reads copy c, which was written by
// convert blocks with blockIdx%8==c, i.e. heuristically the same XCD's L2).
__global__ __launch_bounds__(256) void convert_x_kernel(
    const float* __restrict__ x, uint4* __restrict__ ws) {
    int b = blockIdx.x;                          // 0..511
    int c = b & 7;                               // copy id
    int t = ((b >> 3) << 8) + threadIdx.x;       // granule 0..16383
    int lane = t & 63;
    int h = (t >> 6) & 1;
    int s = (t >> 7) & 1;
    int g = t >> 8;
    int n = lane & 15;
    int q = lane >> 4;
    int bi = h * 16 + n;
    int k0 = g * 64 + q * 16 + s * 8;
    const float4* src = (const float4*)(x + (size_t)bi * IN_F + k0);
    float4 lo = src[0];
    float4 hi = src[1];
    uint4 o;
    o.x = pack2bf(lo.x, lo.y);
    o.y = pack2bf(lo.z, lo.w);
    o.z = pack2bf(hi.x, hi.y);
    o.w = pack2bf(hi.z, hi.w);
    ws[c * 16384 + t] = o;
}

// Kernel 2: MFMA GEMM, v6 — deep-MLP pw staging via global_load_lds.
// Grid: 896 blocks x 1024 threads (16 waves). Block tile: 16 units x 32 batches,
// K-split 16 (wave wid owns groups [wid*4, wid*4+4)).
//
// pw staging: block tile = pw rows u0..u0+15 = 64 KB contiguous in global.
// LDS granule G = g*64 + lane (16 B each); stage issue for group g:
//   LDS base = g*1024 (wave-uniform), lane src = (lane&15)*4096 + g*64 + (lane>>4)*16
// => later ds_read_b128 at byte addr g*1024 + lane*16: perfectly linear,
//    conflict-free, and each wave reads only granules it staged itself
//    (no __syncthreads before the K-loop; one s_waitcnt(0) suffices).
// Reduce buffer (32 KB) aliases the staging LDS after a barrier -> 64 KB/block,
// 2 blocks/CU, 32 waves/CU resident.
__global__ __launch_bounds__(1024, 8) void ternary_mm_kernel(
    const uint4* __restrict__ xw,     // 8 replicated copies of permuted x frags
    const int*   __restrict__ pw,     // [UNITS][PACKED] packed bytes as int32
    const float* __restrict__ scale,
    const float* __restrict__ bias,
    float*       __restrict__ out) {
    __shared__ int lds[16384];        // 64 KB: pw staging, later reduce buffer

    const int tid  = threadIdx.x;
    const int wid  = tid >> 6;           // 0..15 = K-split index
    const int lane = tid & 63;
    const int u0   = blockIdx.x << 4;    // 16 units per block
    const int g0   = wid << 2;           // first group (of 64 total)

    // ---- async-stage this wave's pw slice (groups g0..g0+3) ----
    {
        const char* srcb = (const char*)(pw + (size_t)u0 * PACKED)
                         + (lane & 15) * 4096 + ((lane >> 4) << 4);
        #pragma unroll
        for (int t = 0; t < 4; ++t) {
            const int g = g0 + t;
            __builtin_amdgcn_global_load_lds(
                (const __attribute__((address_space(1))) uint32*)(srcb + (g << 6)),
                (__attribute__((address_space(3))) uint32*)(lds + (g << 8)),
                16, 0, 0);
        }
    }

    // x fragments from this block's XCD-local copy
    const uint4* xb = xw + ((blockIdx.x & 7) * 16384) + (g0 << 8) + lane;
    uint4 xa0 = xb[0], xa1 = xb[64], xa2 = xb[128], xa3 = xb[192];

    __builtin_amdgcn_s_waitcnt(0);       // drain LDS-DMA + first x batch
    __builtin_amdgcn_sched_barrier(0);   // keep ds_reads below the wait

    f32x4 acc0 = {0.f,0.f,0.f,0.f};      // batches h0 (0-15)
    f32x4 acc1 = {0.f,0.f,0.f,0.f};      // batches h1 (16-31)
    const char* lb = (const char*)lds + (lane << 4);

    #pragma unroll
    for (int i = 0; i < 4; ++i) {
        uint4 xn0, xn1, xn2, xn3;
        if (i < 3) {                     // rolling 1-iter x prefetch
            const uint4* xi = xb + ((i + 1) << 8);
            xn0 = xi[0]; xn1 = xi[64]; xn2 = xi[128]; xn3 = xi[192];
        }
        int4 w4 = *(const int4*)(lb + ((g0 + i) << 10));   // ds_read_b128

        uint4 fA, fB;                    // step 0 / step 1 weight frags
        unpack_byte(w4.x, fA.x, fA.y);
        unpack_byte(w4.y, fA.z, fA.w);
        unpack_byte(w4.z, fB.x, fB.y);
        unpack_byte(w4.w, fB.z, fB.w);
        bf16x8 vA = __builtin_bit_cast(bf16x8, fA);
        bf16x8 vB = __builtin_bit_cast(bf16x8, fB);

        acc0 = __builtin_amdgcn_mfma_f32_16x16x32_bf16(
            __builtin_bit_cast(bf16x8, xa0), vA, acc0, 0, 0, 0);
        acc1 = __builtin_amdgcn_mfma_f32_16x16x32_bf16(
            __builtin_bit_cast(bf16x8, xa1), vA, acc1, 0, 0, 0);
        acc0 = __builtin_amdgcn_mfma_f32_16x16x32_bf16(
            __builtin_bit_cast(bf16x8, xa2), vB, acc0, 0, 0, 0);
        acc1 = __builtin_amdgcn_mfma_f32_16x16x32_bf16(
            __builtin_bit_cast(bf16x8, xa3), vB, acc1, 0, 0, 0);

        if (i < 3) { xa0 = xn0; xa1 = xn1; xa2 = xn2; xa3 = xn3; }
    }

    __syncthreads();                     // all pw ds_reads done; alias LDS
    f32x4* red = (f32x4*)lds;            // [16 waves][2 h][64 lanes] = 32 KB
    red[(wid * 2 + 0) * 64 + lane] = acc0;
    red[(wid * 2 + 1) * 64 + lane] = acc1;
    __syncthreads();

    // Reduce 16 K-partials + epilogue. 128 active threads, one per (h, lane).
    if (tid < 128) {
        const int h = tid >> 6;
        const int l = tid & 63;
        f32x4 s = red[h * 64 + l];
        #pragma unroll
        for (int w = 1; w < 16; ++w) {
            f32x4 v = red[(w * 2 + h) * 64 + l];
            s[0] += v[0]; s[1] += v[1]; s[2] += v[2]; s[3] += v[3];
        }
        const int u  = u0 + (l & 15);
        const int b0 = h * 16 + ((l >> 4) << 2);   // row = (lane>>4)*4 + reg
        const float sc = scale[u];
        const float bi = bias[u];
        float* o = out + (size_t)b0 * UNITS + u;
        o[0 * UNITS] = clipf(s[0] * sc + bi);
        o[1 * UNITS] = clipf(s[1] * sc + bi);
        o[2 * UNITS] = clipf(s[2] * sc + bi);
        o[3 * UNITS] = clipf(s[3] * sc + bi);
    }
}

extern "C" void kernel_launch(void* const* d_in, const int* in_sizes, int n_in,
                              void* d_out, int out_size, void* d_ws, size_t ws_size,
                              hipStream_t stream) {
    const float* x     = (const float*)d_in[0];
    const int*   pw    = (const int*)d_in[1];
    const float* scale = (const float*)d_in[2];
    const float* bias  = (const float*)d_in[3];
    float* out = (float*)d_out;

    // ws usage: 8 copies x 256 KB permuted bf16 x fragments = 2 MB
    uint4* xw = (uint4*)d_ws;

    convert_x_kernel<<<512, 256, 0, stream>>>(x, xw);
    ternary_mm_kernel<<<UNITS / 16, 1024, 0, stream>>>(xw, pw, scale, bias, out);
}